// Round 8
// baseline (24344.214 us; speedup 1.0000x reference)
//
#include <hip/hip_runtime.h>
#include <stdint.h>

typedef __attribute__((ext_vector_type(4))) float f32x4;
typedef __attribute__((ext_vector_type(8))) short s16x8;

// ---------------- workspace layout (bytes) ----------------
#define XPK_OFF  0ull
#define WL0_OFF  134217728ull
#define WL1_OFF  176160768ull
#define H0_OFF   218103808ull
#define H1_OFF   218628096ull
#define C0_OFF   219152384ull
#define C1_OFF   219414528ull
#define GP_OFF   219676672ull          // f32 [128][2][5120] split-K partials (5.24 MB)
#define TK_OFF   224919552ull          // u32 [128] tickets
#define WS_NEED  224920064ull

#define OUT_HF 33554432
#define OUT_CF 33685504

static __device__ __forceinline__ float bf2f(unsigned short u){
  unsigned int x = ((unsigned int)u) << 16;
  return __builtin_bit_cast(float, x);
}
static __device__ __forceinline__ unsigned short f2bf(float f){
  unsigned int x = __builtin_bit_cast(unsigned int, f);
  x = x + 0x7FFFu + ((x >> 16) & 1u);   // RNE
  return (unsigned short)(x >> 16);
}
static __device__ __forceinline__ float sigm(float x){ return 1.f/(1.f + __expf(-x)); }
static __device__ __forceinline__ float tanh_(float x){ return 1.f - 2.f/(__expf(2.f*x) + 1.f); }

// ---------------- pack kernels (unchanged, validated round 4) ----------------
__global__ void k_pack_x(const float* __restrict__ x, unsigned short* __restrict__ xpk){
  int tid = blockIdx.x*256 + threadIdx.x;        // 4,194,304 threads
  int row = tid >> 7, k8 = tid & 127;
  int t = row >> 6, m = row & 63;
  const float* src = x + (long)row*1024 + k8*8;
  int frag = (k8>>2)*4 + (m>>4);
  int ln   = (m&15) + ((k8&3)<<4);
  unsigned short* dst = xpk + (long)t*131072 + frag*512 + ln*8;
  s16x8 hi, lo;
  #pragma unroll
  for (int i=0;i<8;++i){
    float v = src[i];
    unsigned short h = f2bf(v);
    hi[i] = (short)h;
    lo[i] = (short)f2bf(v - bf2f(h));
  }
  *(s16x8*)dst = hi;
  *(s16x8*)(dst + 65536) = lo;
}

__global__ void k_pack_w(const float* __restrict__ wall, const float* __restrict__ wt,
                         unsigned short* __restrict__ dst, int layer){
  int tid = blockIdx.x*256 + threadIdx.x;        // 1,310,720 threads
  int grp = tid >> 12;                           // 0..319
  int fi  = (tid >> 6) & 63;                     // k/32
  int slot= tid & 63;
  int jj  = slot & 15;
  int k   = (fi*4 + (slot>>4)) * 8;
  int c   = grp / 5, gi = grp % 5;
  const float* src = nullptr;
  bool zero = false;
  if (gi < 4){
    int row = gi*1024 + c*16 + jj;
    int sk = (layer==0) ? ((k < 1024) ? 1024 + k : k - 1024) : k;
    src = wall + (long)row*2048 + sk;
  } else {
    if (layer == 0){
      if (k >= 1024) src = wt + (long)(c*16+jj)*1024 + (k-1024); else zero = true;
    } else {
      if (k < 1024)  src = wt + (long)(c*16+jj)*1024 + k;        else zero = true;
    }
  }
  s16x8 hi, lo;
  #pragma unroll
  for (int i=0;i<8;++i){
    float v = zero ? 0.f : src[i];
    unsigned short h = f2bf(v);
    hi[i] = (short)h;
    lo[i] = (short)f2bf(v - bf2f(h));
  }
  long base = (long)(grp*64 + fi)*512 + slot*8;
  *(s16x8*)(dst + base) = hi;
  *(s16x8*)(dst + 10485760 + base) = lo;
}

// ---------------- per-step kernel: split-K + last-block epilogue ----------------
// 256 blocks: pid = bid>>1 (layer = pid>>6, c = pid&63), khalf = bid&1.
// Block reads ONLY its K-half of the weights (unique bytes chip-wide).
// 4 waves = (mh, kq): m-rows mh*32..+31, K-slice khalf*1024 + kq*512.
// In-block: R[mh] kq0-write/kq1-add. Cross-block: device-scope store of the
// 64x80 half-tile + ticket; last block sums and does the cell phase.
__global__ __launch_bounds__(256, 2) void k_step(
    const unsigned short* __restrict__ xpk,
    const unsigned short* __restrict__ wl0,
    const unsigned short* __restrict__ wl1,
    unsigned short* __restrict__ h0pk,
    unsigned short* __restrict__ h1pk,
    float* __restrict__ c0, float* __restrict__ c1,
    const float* __restrict__ ball0, const float* __restrict__ bt0,
    const float* __restrict__ ball1, const float* __restrict__ bt1,
    float* __restrict__ gpart, unsigned int* __restrict__ ticket,
    float* __restrict__ out, int s)
{
  __shared__ float R[2][32*84];
  __shared__ float T[5120];
  __shared__ int lastFlag;
  const int bid = blockIdx.x;
  const int pid = bid >> 1, khalf = bid & 1;
  const int layer = pid >> 6;
  const int c = pid & 63;
  if (layer == 0 && s >= 512) return;
  if (layer == 1 && s == 0) return;
  const int tid = threadIdx.x;
  const int lane = tid & 63, w = tid >> 6;
  const int mh = w >> 1, kq = w & 1;

  // ---- GEMM phase: 32x80 tile over this wave's 512-K slice, bf16x3 ----
  f32x4 acc[2][5];
  #pragma unroll
  for (int a=0;a<2;++a)
    #pragma unroll
    for (int b=0;b<5;++b) acc[a][b] = (f32x4){0.f,0.f,0.f,0.f};
  {
    const unsigned short *Asrc, *W;
    bool useA;
    if (layer == 0){
      W = wl0;
      if (khalf == 0){ Asrc = h0pk + (size_t)((s+1)&1)*131072; useA = (s > 0); }
      else           { Asrc = xpk  + (size_t)s*131072;         useA = true;    }
    } else {
      W = wl1;
      if (khalf == 0){ Asrc = h0pk + (size_t)((s+1)&1)*131072; useA = true;     }
      else           { Asrc = h1pk + (size_t)(s&1)*131072;     useA = (s >= 2); }
    }
    const s16x8* Abase = (const s16x8*)Asrc;
    const s16x8* Bv    = (const s16x8*)W;
    const int a0 = kq*64 + mh*2;
    const int b0 = c*320 + khalf*32 + kq*16;
    // tx weights are structurally zero in: L0 h-half (khalf0); L1 h1-half (khalf1)
    const bool doTx = (layer == 0) ? (khalf == 1) : (khalf == 0);

    const s16x8 zz = {0,0,0,0,0,0,0,0};
    s16x8 ah[2][2], al[2][2], bh[2][5], bl[2][5];
    auto ldfr = [&](int buf, int ks){
      #pragma unroll
      for (int mf=0; mf<2; ++mf){
        int f = (a0 + ks*4 + mf)*64 + lane;
        ah[buf][mf] = useA ? Abase[f] : zz;
        al[buf][mf] = useA ? Abase[8192 + f] : zz;
      }
      #pragma unroll
      for (int nf=0; nf<4; ++nf){
        int f = (b0 + nf*64 + ks)*64 + lane;
        bh[buf][nf] = Bv[f];
        bl[buf][nf] = Bv[1310720 + f];
      }
      if (doTx){
        int f = (b0 + 4*64 + ks)*64 + lane;
        bh[buf][4] = Bv[f];
        bl[buf][4] = Bv[1310720 + f];
      }
    };
    ldfr(0, 0);
    #pragma unroll
    for (int ks=0; ks<16; ++ks){
      const int cur = ks & 1;
      if (ks < 15) ldfr(cur ^ 1, ks + 1);
      #pragma unroll
      for (int mf=0; mf<2; ++mf)
        #pragma unroll
        for (int nf=0; nf<4; ++nf){
          acc[mf][nf] = __builtin_amdgcn_mfma_f32_16x16x32_bf16(ah[cur][mf], bh[cur][nf], acc[mf][nf], 0, 0, 0);
          acc[mf][nf] = __builtin_amdgcn_mfma_f32_16x16x32_bf16(al[cur][mf], bh[cur][nf], acc[mf][nf], 0, 0, 0);
          acc[mf][nf] = __builtin_amdgcn_mfma_f32_16x16x32_bf16(ah[cur][mf], bl[cur][nf], acc[mf][nf], 0, 0, 0);
        }
      if (doTx){
        #pragma unroll
        for (int mf=0; mf<2; ++mf){
          acc[mf][4] = __builtin_amdgcn_mfma_f32_16x16x32_bf16(ah[cur][mf], bh[cur][4], acc[mf][4], 0, 0, 0);
          acc[mf][4] = __builtin_amdgcn_mfma_f32_16x16x32_bf16(al[cur][mf], bh[cur][4], acc[mf][4], 0, 0, 0);
          acc[mf][4] = __builtin_amdgcn_mfma_f32_16x16x32_bf16(ah[cur][mf], bl[cur][4], acc[mf][4], 0, 0, 0);
        }
      }
    }
  }

  // ---- in-block reduce: per-mh buffer, kq0 writes, kq1 adds ----
  {
    float* Rm = R[mh];
    if (kq == 0){
      #pragma unroll
      for (int mf=0; mf<2; ++mf)
        #pragma unroll
        for (int nf=0; nf<5; ++nf)
          #pragma unroll
          for (int r=0; r<4; ++r){
            int ml = mf*16 + (lane>>4)*4 + r;
            int n  = nf*16 + (lane&15);
            Rm[ml*84 + n] = acc[mf][nf][r];
          }
    }
    __syncthreads();
    if (kq == 1){
      #pragma unroll
      for (int mf=0; mf<2; ++mf)
        #pragma unroll
        for (int nf=0; nf<5; ++nf)
          #pragma unroll
          for (int r=0; r<4; ++r){
            int ml = mf*16 + (lane>>4)*4 + r;
            int n  = nf*16 + (lane&15);
            Rm[ml*84 + n] += acc[mf][nf][r];
          }
    }
    __syncthreads();
  }

  // ---- publish half-tile (device scope) + ticket ----
  float* gme = gpart + ((size_t)pid*2 + khalf)*5120;
  float* got = gpart + ((size_t)pid*2 + (khalf^1))*5120;
  #pragma unroll
  for (int k2=0; k2<20; ++k2){
    int i = k2*256 + tid;
    int m = i / 80, n = i % 80;
    float own = R[m>>5][(m&31)*84 + n];
    __hip_atomic_store(gme + i, own, __ATOMIC_RELAXED, __HIP_MEMORY_SCOPE_AGENT);
  }
  __threadfence();          // drain stores to the coherent point (per-wave vmcnt)
  __syncthreads();          // all waves drained
  if (tid == 0){
    unsigned int old = __hip_atomic_fetch_add(ticket + pid, 1u, __ATOMIC_ACQ_REL, __HIP_MEMORY_SCOPE_AGENT);
    lastFlag = (old == 1);
    if (old == 1) __hip_atomic_store(ticket + pid, 0u, __ATOMIC_RELAXED, __HIP_MEMORY_SCOPE_AGENT);
  }
  __syncthreads();
  if (!lastFlag) return;

  // ---- epilogue (last block only): combine halves, cell update ----
  #pragma unroll
  for (int k2=0; k2<20; ++k2){
    int i = k2*256 + tid;
    int m = i / 80, n = i % 80;
    float oth = __hip_atomic_load(got + i, __ATOMIC_RELAXED, __HIP_MEMORY_SCOPE_AGENT);
    T[i] = R[m>>5][(m&31)*84 + n] + oth;
  }
  __syncthreads();

  const int e = (layer == 0) ? s : s - 1;
  const float* ball = layer ? ball1 : ball0;
  const float* bt   = layer ? bt1   : bt0;
  float* cs = layer ? c1 : c0;
  unsigned short* hp = (layer ? h1pk : h0pk) + (size_t)(e&1)*131072;

  #pragma unroll
  for (int it=0; it<4; ++it){
    int idx = it*256 + tid;
    int m = idx >> 4, jj = idx & 15;
    int j = c*16 + jj;
    float pre[4];
    #pragma unroll
    for (int g=0; g<4; ++g)
      pre[g] = T[m*80 + g*16 + jj] + ball[g*1024 + j];
    float tx = T[m*80 + 64 + jj] + bt[j];
    float ii = sigm(pre[0]), ff = sigm(pre[1]), oo = sigm(pre[2]);
    float gt = tanh_(tx * pre[3]);
    float cold = (e == 0) ? 0.f : cs[m*1024 + j];
    float cc = ff*cold + ii*gt;
    cs[m*1024 + j] = cc;
    float hh = oo*tanh_(cc);
    int fr = (j>>5)*4 + (m>>4);
    int ln = (m&15) + (((j>>3)&3)<<4);
    unsigned short hb = f2bf(hh);
    hp[fr*512 + ln*8 + (j&7)] = hb;
    hp[65536 + fr*512 + ln*8 + (j&7)] = f2bf(hh - bf2f(hb));
    if (layer){
      out[(size_t)e*65536 + m*1024 + j] = hh;
      if (e == 511){ out[OUT_HF + 65536 + m*1024 + j] = hh; out[OUT_CF + 65536 + m*1024 + j] = cc; }
    } else if (e == 511){
      out[OUT_HF + m*1024 + j] = hh; out[OUT_CF + m*1024 + j] = cc;
    }
  }
}

extern "C" void kernel_launch(void* const* d_in, const int* in_sizes, int n_in,
                              void* d_out, int out_size, void* d_ws, size_t ws_size,
                              hipStream_t stream)
{
  (void)in_sizes; (void)n_in;
  const float* x     = (const float*)d_in[0];
  const float* wall0 = (const float*)d_in[1];
  const float* ball0 = (const float*)d_in[2];
  const float* wt0   = (const float*)d_in[3];
  const float* bt0   = (const float*)d_in[4];
  const float* wall1 = (const float*)d_in[5];
  const float* ball1 = (const float*)d_in[6];
  const float* wt1   = (const float*)d_in[7];
  const float* bt1   = (const float*)d_in[8];
  float* out = (float*)d_out;
  char* ws = (char*)d_ws;

  if (ws_size < WS_NEED){
    hipMemsetAsync(d_out, 0, (size_t)out_size*4, stream);  // visible failure, no OOB
    return;
  }

  unsigned short* xpk = (unsigned short*)(ws + XPK_OFF);
  unsigned short* wl0 = (unsigned short*)(ws + WL0_OFF);
  unsigned short* wl1 = (unsigned short*)(ws + WL1_OFF);
  unsigned short* h0p = (unsigned short*)(ws + H0_OFF);
  unsigned short* h1p = (unsigned short*)(ws + H1_OFF);
  float* c0 = (float*)(ws + C0_OFF);
  float* c1 = (float*)(ws + C1_OFF);
  float* gpart = (float*)(ws + GP_OFF);
  unsigned int* ticket = (unsigned int*)(ws + TK_OFF);

  hipMemsetAsync(ws + TK_OFF, 0, 512, stream);
  k_pack_x<<<16384, 256, 0, stream>>>(x, xpk);
  k_pack_w<<<5120, 256, 0, stream>>>(wall0, wt0, wl0, 0);
  k_pack_w<<<5120, 256, 0, stream>>>(wall1, wt1, wl1, 1);

  for (int s = 0; s <= 512; ++s){
    k_step<<<256, 256, 0, stream>>>(xpk, wl0, wl1, h0p, h1p, c0, c1,
                                    ball0, bt0, ball1, bt1, gpart, ticket, out, s);
  }
}

// Round 9
// 10854.561 us; speedup vs baseline: 2.2428x; 2.2428x over previous
//
#include <hip/hip_runtime.h>
#include <stdint.h>

typedef __attribute__((ext_vector_type(4))) float f32x4;
typedef __attribute__((ext_vector_type(8))) short s16x8;

// ---------------- workspace layout (bytes) ----------------
#define XPK_OFF  0ull
#define WL0_OFF  134217728ull
#define WL1_OFF  176160768ull
#define H0_OFF   218103808ull
#define H1_OFF   218628096ull
#define C0_OFF   219152384ull
#define C1_OFF   219414528ull
#define GP_OFF   219676672ull          // f32 [128][4][5120] split-K partials (10.5 MB)
#define WS_NEED  230162432ull

#define OUT_HF 33554432
#define OUT_CF 33685504

static __device__ __forceinline__ float bf2f(unsigned short u){
  unsigned int x = ((unsigned int)u) << 16;
  return __builtin_bit_cast(float, x);
}
static __device__ __forceinline__ unsigned short f2bf(float f){
  unsigned int x = __builtin_bit_cast(unsigned int, f);
  x = x + 0x7FFFu + ((x >> 16) & 1u);   // RNE
  return (unsigned short)(x >> 16);
}
static __device__ __forceinline__ float sigm(float x){ return 1.f/(1.f + __expf(-x)); }
static __device__ __forceinline__ float tanh_(float x){ return 1.f - 2.f/(__expf(2.f*x) + 1.f); }

// ---------------- pack kernels (unchanged, validated round 4) ----------------
__global__ void k_pack_x(const float* __restrict__ x, unsigned short* __restrict__ xpk){
  int tid = blockIdx.x*256 + threadIdx.x;        // 4,194,304 threads
  int row = tid >> 7, k8 = tid & 127;
  int t = row >> 6, m = row & 63;
  const float* src = x + (long)row*1024 + k8*8;
  int frag = (k8>>2)*4 + (m>>4);
  int ln   = (m&15) + ((k8&3)<<4);
  unsigned short* dst = xpk + (long)t*131072 + frag*512 + ln*8;
  s16x8 hi, lo;
  #pragma unroll
  for (int i=0;i<8;++i){
    float v = src[i];
    unsigned short h = f2bf(v);
    hi[i] = (short)h;
    lo[i] = (short)f2bf(v - bf2f(h));
  }
  *(s16x8*)dst = hi;
  *(s16x8*)(dst + 65536) = lo;
}

__global__ void k_pack_w(const float* __restrict__ wall, const float* __restrict__ wt,
                         unsigned short* __restrict__ dst, int layer){
  int tid = blockIdx.x*256 + threadIdx.x;        // 1,310,720 threads
  int grp = tid >> 12;                           // 0..319
  int fi  = (tid >> 6) & 63;                     // k/32
  int slot= tid & 63;
  int jj  = slot & 15;
  int k   = (fi*4 + (slot>>4)) * 8;
  int c   = grp / 5, gi = grp % 5;
  const float* src = nullptr;
  bool zero = false;
  if (gi < 4){
    int row = gi*1024 + c*16 + jj;
    int sk = (layer==0) ? ((k < 1024) ? 1024 + k : k - 1024) : k;
    src = wall + (long)row*2048 + sk;
  } else {
    if (layer == 0){
      if (k >= 1024) src = wt + (long)(c*16+jj)*1024 + (k-1024); else zero = true;
    } else {
      if (k < 1024)  src = wt + (long)(c*16+jj)*1024 + k;        else zero = true;
    }
  }
  s16x8 hi, lo;
  #pragma unroll
  for (int i=0;i<8;++i){
    float v = zero ? 0.f : src[i];
    unsigned short h = f2bf(v);
    hi[i] = (short)h;
    lo[i] = (short)f2bf(v - bf2f(h));
  }
  long base = (long)(grp*64 + fi)*512 + slot*8;
  *(s16x8*)(dst + base) = hi;
  *(s16x8*)(dst + 10485760 + base) = lo;
}

// ---------------- GEMM kernel: 512 blocks = (pid, K-quarter) ----------------
// pid = bid>>2 (layer = pid>>6, c = pid&63), kq = bid&3 (K window kq*512).
// Each block reads a UNIQUE 512-K slice of the weights (147 KB) -> no duplicate
// weight traffic chip-wide; 2 blocks/CU for TLP. 4 waves = (mh, ks):
// rows mh*32..+31, K-sub-slice ks*256. Partials -> gpart[pid][kq][5120], plain
// coalesced stores; stream order to k_cell is the only synchronization.
__global__ __launch_bounds__(256, 2) void k_gemm(
    const unsigned short* __restrict__ xpk,
    const unsigned short* __restrict__ wl0,
    const unsigned short* __restrict__ wl1,
    const unsigned short* __restrict__ h0pk,
    const unsigned short* __restrict__ h1pk,
    float* __restrict__ gpart, int s)
{
  __shared__ float R[2][32*84];
  const int bid = blockIdx.x;
  const int pid = bid >> 2, kq = bid & 3;
  const int layer = pid >> 6;
  const int c = pid & 63;
  if (layer == 0 && s >= 512) return;
  if (layer == 1 && s == 0) return;
  const int khalf = kq >> 1, kqs = kq & 1;
  const int tid = threadIdx.x;
  const int lane = tid & 63, w = tid >> 6;
  const int mh = w >> 1, ks = w & 1;

  // ---- GEMM: 32x80 tile over this wave's 256-K slice, bf16x3 ----
  f32x4 acc[2][5];
  #pragma unroll
  for (int a=0;a<2;++a)
    #pragma unroll
    for (int b=0;b<5;++b) acc[a][b] = (f32x4){0.f,0.f,0.f,0.f};
  {
    const unsigned short *Asrc, *W;
    bool useA;
    if (layer == 0){
      W = wl0;
      if (khalf == 0){ Asrc = h0pk + (size_t)((s+1)&1)*131072; useA = (s > 0); }
      else           { Asrc = xpk  + (size_t)s*131072;         useA = true;    }
    } else {
      W = wl1;
      if (khalf == 0){ Asrc = h0pk + (size_t)((s+1)&1)*131072; useA = true;     }
      else           { Asrc = h1pk + (size_t)(s&1)*131072;     useA = (s >= 2); }
    }
    const s16x8* Abase = (const s16x8*)Asrc;
    const s16x8* Bv    = (const s16x8*)W;
    const int a0 = kqs*64 + ks*32 + mh*2;
    const int b0 = c*320 + khalf*32 + kqs*16 + ks*8;
    // tx weights structurally zero in: L0 h-half (khalf0); L1 h1-half (khalf1)
    const bool doTx = (layer == 0) ? (khalf == 1) : (khalf == 0);

    const s16x8 zz = {0,0,0,0,0,0,0,0};
    s16x8 ah[2][2], al[2][2], bh[2][5], bl[2][5];
    auto ldfr = [&](int buf, int kk){
      #pragma unroll
      for (int mf=0; mf<2; ++mf){
        int f = (a0 + kk*4 + mf)*64 + lane;
        ah[buf][mf] = useA ? Abase[f] : zz;
        al[buf][mf] = useA ? Abase[8192 + f] : zz;
      }
      #pragma unroll
      for (int nf=0; nf<4; ++nf){
        int f = (b0 + nf*64 + kk)*64 + lane;
        bh[buf][nf] = Bv[f];
        bl[buf][nf] = Bv[1310720 + f];
      }
      if (doTx){
        int f = (b0 + 4*64 + kk)*64 + lane;
        bh[buf][4] = Bv[f];
        bl[buf][4] = Bv[1310720 + f];
      }
    };
    ldfr(0, 0);
    #pragma unroll
    for (int kk=0; kk<8; ++kk){
      const int cur = kk & 1;
      if (kk < 7) ldfr(cur ^ 1, kk + 1);
      #pragma unroll
      for (int mf=0; mf<2; ++mf)
        #pragma unroll
        for (int nf=0; nf<4; ++nf){
          acc[mf][nf] = __builtin_amdgcn_mfma_f32_16x16x32_bf16(ah[cur][mf], bh[cur][nf], acc[mf][nf], 0, 0, 0);
          acc[mf][nf] = __builtin_amdgcn_mfma_f32_16x16x32_bf16(al[cur][mf], bh[cur][nf], acc[mf][nf], 0, 0, 0);
          acc[mf][nf] = __builtin_amdgcn_mfma_f32_16x16x32_bf16(ah[cur][mf], bl[cur][nf], acc[mf][nf], 0, 0, 0);
        }
      if (doTx){
        #pragma unroll
        for (int mf=0; mf<2; ++mf){
          acc[mf][4] = __builtin_amdgcn_mfma_f32_16x16x32_bf16(ah[cur][mf], bh[cur][4], acc[mf][4], 0, 0, 0);
          acc[mf][4] = __builtin_amdgcn_mfma_f32_16x16x32_bf16(al[cur][mf], bh[cur][4], acc[mf][4], 0, 0, 0);
          acc[mf][4] = __builtin_amdgcn_mfma_f32_16x16x32_bf16(ah[cur][mf], bl[cur][4], acc[mf][4], 0, 0, 0);
        }
      }
    }
  }

  // ---- in-block reduce: per-mh buffer, ks0 writes, ks1 adds ----
  {
    float* Rm = R[mh];
    if (ks == 0){
      #pragma unroll
      for (int mf=0; mf<2; ++mf)
        #pragma unroll
        for (int nf=0; nf<5; ++nf)
          #pragma unroll
          for (int r=0; r<4; ++r){
            int ml = mf*16 + (lane>>4)*4 + r;
            int n  = nf*16 + (lane&15);
            Rm[ml*84 + n] = acc[mf][nf][r];
          }
    }
    __syncthreads();
    if (ks == 1){
      #pragma unroll
      for (int mf=0; mf<2; ++mf)
        #pragma unroll
        for (int nf=0; nf<5; ++nf)
          #pragma unroll
          for (int r=0; r<4; ++r){
            int ml = mf*16 + (lane>>4)*4 + r;
            int n  = nf*16 + (lane&15);
            Rm[ml*84 + n] += acc[mf][nf][r];
          }
    }
    __syncthreads();
  }

  // ---- publish 64x80 partial tile: plain coalesced stores ----
  float* gme = gpart + ((size_t)pid*4 + kq)*5120;
  #pragma unroll
  for (int k2=0; k2<20; ++k2){
    int i = k2*256 + tid;
    int m = i / 80, n = i % 80;
    gme[i] = R[m>>5][(m&31)*84 + n];
  }
}

// ---------------- cell kernel: 128 blocks = pid ----------------
__global__ __launch_bounds__(256) void k_cell(
    unsigned short* __restrict__ h0pk,
    unsigned short* __restrict__ h1pk,
    float* __restrict__ c0, float* __restrict__ c1,
    const float* __restrict__ ball0, const float* __restrict__ bt0,
    const float* __restrict__ ball1, const float* __restrict__ bt1,
    const float* __restrict__ gpart, float* __restrict__ out, int s)
{
  __shared__ float T[5120];
  const int pid = blockIdx.x;
  const int layer = pid >> 6;
  const int c = pid & 63;
  if (layer == 0 && s >= 512) return;
  if (layer == 1 && s == 0) return;
  const int tid = threadIdx.x;

  // sum the 4 K-quarter partials (fixed order -> deterministic)
  const f32x4* g0 = (const f32x4*)(gpart + (size_t)pid*4*5120);
  #pragma unroll
  for (int q=0; q<5; ++q){
    int idx = q*256 + tid;             // 1280 f32x4 elements
    f32x4 v = g0[idx] + g0[1280 + idx] + g0[2560 + idx] + g0[3840 + idx];
    ((f32x4*)T)[idx] = v;
  }
  __syncthreads();

  const int e = (layer == 0) ? s : s - 1;
  const float* ball = layer ? ball1 : ball0;
  const float* bt   = layer ? bt1   : bt0;
  float* cs = layer ? c1 : c0;
  unsigned short* hp = (layer ? h1pk : h0pk) + (size_t)(e&1)*131072;

  #pragma unroll
  for (int it=0; it<4; ++it){
    int idx = it*256 + tid;
    int m = idx >> 4, jj = idx & 15;
    int j = c*16 + jj;
    float pre[4];
    #pragma unroll
    for (int g=0; g<4; ++g)
      pre[g] = T[m*80 + g*16 + jj] + ball[g*1024 + j];
    float tx = T[m*80 + 64 + jj] + bt[j];
    float ii = sigm(pre[0]), ff = sigm(pre[1]), oo = sigm(pre[2]);
    float gt = tanh_(tx * pre[3]);
    float cold = (e == 0) ? 0.f : cs[m*1024 + j];
    float cc = ff*cold + ii*gt;
    cs[m*1024 + j] = cc;
    float hh = oo*tanh_(cc);
    int fr = (j>>5)*4 + (m>>4);
    int ln = (m&15) + (((j>>3)&3)<<4);
    unsigned short hb = f2bf(hh);
    hp[fr*512 + ln*8 + (j&7)] = hb;
    hp[65536 + fr*512 + ln*8 + (j&7)] = f2bf(hh - bf2f(hb));
    if (layer){
      out[(size_t)e*65536 + m*1024 + j] = hh;
      if (e == 511){ out[OUT_HF + 65536 + m*1024 + j] = hh; out[OUT_CF + 65536 + m*1024 + j] = cc; }
    } else if (e == 511){
      out[OUT_HF + m*1024 + j] = hh; out[OUT_CF + m*1024 + j] = cc;
    }
  }
}

extern "C" void kernel_launch(void* const* d_in, const int* in_sizes, int n_in,
                              void* d_out, int out_size, void* d_ws, size_t ws_size,
                              hipStream_t stream)
{
  (void)in_sizes; (void)n_in;
  const float* x     = (const float*)d_in[0];
  const float* wall0 = (const float*)d_in[1];
  const float* ball0 = (const float*)d_in[2];
  const float* wt0   = (const float*)d_in[3];
  const float* bt0   = (const float*)d_in[4];
  const float* wall1 = (const float*)d_in[5];
  const float* ball1 = (const float*)d_in[6];
  const float* wt1   = (const float*)d_in[7];
  const float* bt1   = (const float*)d_in[8];
  float* out = (float*)d_out;
  char* ws = (char*)d_ws;

  if (ws_size < WS_NEED){
    hipMemsetAsync(d_out, 0, (size_t)out_size*4, stream);  // visible failure, no OOB
    return;
  }

  unsigned short* xpk = (unsigned short*)(ws + XPK_OFF);
  unsigned short* wl0 = (unsigned short*)(ws + WL0_OFF);
  unsigned short* wl1 = (unsigned short*)(ws + WL1_OFF);
  unsigned short* h0p = (unsigned short*)(ws + H0_OFF);
  unsigned short* h1p = (unsigned short*)(ws + H1_OFF);
  float* c0 = (float*)(ws + C0_OFF);
  float* c1 = (float*)(ws + C1_OFF);
  float* gpart = (float*)(ws + GP_OFF);

  k_pack_x<<<16384, 256, 0, stream>>>(x, xpk);
  k_pack_w<<<5120, 256, 0, stream>>>(wall0, wt0, wl0, 0);
  k_pack_w<<<5120, 256, 0, stream>>>(wall1, wt1, wl1, 1);

  for (int s = 0; s <= 512; ++s){
    k_gemm<<<512, 256, 0, stream>>>(xpk, wl0, wl1, h0p, h1p, gpart, s);
    k_cell<<<128, 256, 0, stream>>>(h0p, h1p, c0, c1,
                                    ball0, bt0, ball1, bt1, gpart, out, s);
  }
}